// Round 8
// baseline (433.627 us; speedup 1.0000x reference)
//
#include <hip/hip_runtime.h>
#include <stdint.h>

// ---------- types ----------
typedef __attribute__((ext_vector_type(8))) short short8;   // 8 bf16 (4 VGPRs)
typedef __attribute__((ext_vector_type(4))) short short4v;
typedef __attribute__((ext_vector_type(4))) float f32x4;

typedef __attribute__((address_space(1))) void as1_void;
typedef __attribute__((address_space(3))) void as3_void;

#define B_SZ 2
#define L_SZ 2048
#define DM   1024
#define DI   2048
#define DS   16
#define NROW 4096          // B_SZ * L_SZ
#define NC   8             // scan chunks
#define CL   256           // chunk length
#define PP   36            // proj row pitch (padded from 33 for aligned float4)

__device__ __forceinline__ short f2bf(float f) {
    unsigned u = __float_as_uint(f);
    u += 0x7FFF + ((u >> 16) & 1);           // RNE
    return (short)(u >> 16);
}

__device__ __forceinline__ void gl2lds16(const void* g, void* l) {
    __builtin_amdgcn_global_load_lds((as1_void*)(void*)(uintptr_t)(const_cast<void*>(g)),
                                     (as3_void*)l, 16, 0, 0);
}

template<int CTRL>
__device__ __forceinline__ float dpp_shr(float x) {
    int i = __float_as_int(x);
    i = __builtin_amdgcn_update_dpp(0, i, CTRL, 0xF, 0xF, true);
    return __int_as_float(i);
}

// ---------- convert x -> bf16 ----------
__global__ __launch_bounds__(256) void convert_x_k(const float* __restrict__ x,
                                                   short* __restrict__ xbf) {
    int idx = blockIdx.x * 256 + threadIdx.x;      // over 4M/4 groups
    float4 v = ((const float4*)x)[idx];
    short4v o;
    o.x = f2bf(v.x); o.y = f2bf(v.y); o.z = f2bf(v.z); o.w = f2bf(v.w);
    ((short4v*)xbf)[idx] = o;
}

// ---------- transpose KxN fp32 -> NxK bf16 ----------
__global__ __launch_bounds__(256) void transpose_to_bf16(const float* __restrict__ in,
                                                         short* __restrict__ out,
                                                         int K, int N) {
    __shared__ float tile[32][33];
    int tx = threadIdx.x & 31, ty = threadIdx.x >> 5;   // 32 x 8
    int n0 = blockIdx.x * 32, k0 = blockIdx.y * 32;
    #pragma unroll
    for (int i = 0; i < 4; i++) {
        int r = ty + i * 8;
        tile[r][tx] = in[(long)(k0 + r) * N + n0 + tx];
    }
    __syncthreads();
    #pragma unroll
    for (int i = 0; i < 4; i++) {
        int r = ty + i * 8;
        out[(long)(n0 + r) * K + k0 + tx] = f2bf(tile[tx][r]);
    }
}

// ---------- bf16 MFMA GEMM:  C(MxN) = A(MxK) * BT(NxK)^T + bias ----------
// Anti-lockstep (R6/R7): diagonal (bm,bn) remap + per-block K-phase rotation.
// NOTE: gridDim.x must be a power of two (32 for GEMM1, 8 for GEMM3).
// R7 bug: conditional-subtract wrap overflowed for gridDim.x=8 -> OOB. Use mask.
#define BM 128
#define BN 128
#define BK 32
__global__ __launch_bounds__(256) void gemm_bt(const short* __restrict__ A,
                                               const short* __restrict__ BT,
                                               float* __restrict__ C,
                                               const float* __restrict__ bias,
                                               int M, int N, int K) {
    __shared__ __align__(16) short As[BM * BK];   // 8 KB
    __shared__ __align__(16) short Bs[BN * BK];   // 8 KB
    const int tid  = threadIdx.x;
    const int w    = tid >> 6;
    const int lane = tid & 63;

    const int lid = blockIdx.x + gridDim.x * blockIdx.y;
    const int bn_i = (blockIdx.x + blockIdx.y) & (gridDim.x - 1);   // diagonal remap
    const int bm = blockIdx.y * BM, bn = bn_i * BN;

    const int nit = K >> 5;                         // K/BK (power of 2: 32 or 64)
    const int phase = ((lid >> 3) * 7 + (lid & 7)) & (nit - 1);

    const int wm = (w & 1) * 64, wn = (w >> 1) * 64;
    const int quad = lane >> 4, r16 = lane & 15;

    const int srow = w * 16 + (lane >> 2);
    const int scol = (lane & 3) * 8;
    const short* Ag = A  + (long)(bm + srow) * K + scol;
    const short* Bg = BT + (long)(bn + srow) * K + scol;
    char* AsB = (char*)As + w * 1024;
    char* BsB = (char*)Bs + w * 1024;

    f32x4 acc[4][4] = {};
    for (int kk = 0; kk < nit; kk++) {
        int ki = kk + phase; if (ki >= nit) ki -= nit;
        int k0 = ki << 5;
        __syncthreads();
        gl2lds16(Ag + k0,                  AsB);
        gl2lds16(Ag + (long)64 * K + k0,   AsB + 4096);
        gl2lds16(Bg + k0,                  BsB);
        gl2lds16(Bg + (long)64 * K + k0,   BsB + 4096);
        __syncthreads();

        short8 af[4], bfr[4];
        #pragma unroll
        for (int i = 0; i < 4; i++)
            af[i] = *(const short8*)&As[(wm + i * 16 + r16) * BK + quad * 8];
        #pragma unroll
        for (int j = 0; j < 4; j++)
            bfr[j] = *(const short8*)&Bs[(wn + j * 16 + r16) * BK + quad * 8];
        #pragma unroll
        for (int i = 0; i < 4; i++)
            #pragma unroll
            for (int j = 0; j < 4; j++)
                acc[i][j] = __builtin_amdgcn_mfma_f32_16x16x32_bf16(af[i], bfr[j], acc[i][j], 0, 0, 0);
    }
    #pragma unroll
    for (int i = 0; i < 4; i++) {
        #pragma unroll
        for (int j = 0; j < 4; j++) {
            int col = bn + wn + j * 16 + r16;
            float bv = bias[col];
            #pragma unroll
            for (int r = 0; r < 4; r++) {
                int row = bm + wm + i * 16 + quad * 4 + r;
                C[(long)row * N + col] = acc[i][j][r] + bv;
            }
        }
    }
}

// ---------- depthwise causal conv (k=4) + SiLU ----------
__global__ __launch_bounds__(256) void conv_silu_k(const float* __restrict__ xz,
                                                   const float* __restrict__ cw,
                                                   const float* __restrict__ cb,
                                                   float* __restrict__ xc) {
    int idx = blockIdx.x * 256 + threadIdx.x;    // 4096 rows * 512 d-groups
    int dg = idx & 511;
    int row = idx >> 9;
    int t = row & (L_SZ - 1);
    int d = dg * 4;
    float4 acc = *(const float4*)(cb + d);
    float4 c0 = *(const float4*)(cw + (d + 0) * 4);
    float4 c1 = *(const float4*)(cw + (d + 1) * 4);
    float4 c2 = *(const float4*)(cw + (d + 2) * 4);
    float4 c3 = *(const float4*)(cw + (d + 3) * 4);
    const float cw0[4] = {c0.x, c0.y, c0.z, c0.w};
    const float cw1[4] = {c1.x, c1.y, c1.z, c1.w};
    const float cw2[4] = {c2.x, c2.y, c2.z, c2.w};
    const float cw3[4] = {c3.x, c3.y, c3.z, c3.w};
    #pragma unroll
    for (int k = 0; k < 4; k++) {
        int tt = t - 3 + k;
        if (tt >= 0) {
            float4 xv = *(const float4*)(xz + (long)(row - 3 + k) * 4096 + d);
            acc.x += xv.x * cw0[k];
            acc.y += xv.y * cw1[k];
            acc.z += xv.z * cw2[k];
            acc.w += xv.w * cw3[k];
        }
    }
    float4 o;
    o.x = acc.x / (1.f + __expf(-acc.x));
    o.y = acc.y / (1.f + __expf(-acc.y));
    o.z = acc.z / (1.f + __expf(-acc.z));
    o.w = acc.w / (1.f + __expf(-acc.w));
    *(float4*)(xc + (long)row * DI + d) = o;
}

// ---------- proj = xc @ W_xproj  (wave per row; Wx chunks staged in LDS) ----------
// Decorrelated chunk/staging order per block to avoid L2 same-line serialization (R5).
#define PWC 256            // k-chunk staged per iteration
__global__ __launch_bounds__(256) void proj_gemm(const float* __restrict__ xc,
                                                 const float* __restrict__ Wx,
                                                 float* __restrict__ proj) {
    __shared__ float s_w[PWC * 33];            // 33.8 KB
    const int tid = threadIdx.x;
    const int w = tid >> 6, lane = tid & 63;
    const int bx = blockIdx.x;
    const long row = (long)bx * 4 + w;
    const int phase = (bx >> 3) & 7;           // chunk-order stagger
    const int irot  = (bx * 7) & 31;           // staging-order rotation (<33)

    float acc[33];
    #pragma unroll
    for (int j = 0; j < 33; j++) acc[j] = 0.f;

    for (int cc = 0; cc < DI / PWC; cc++) {
        int c = cc + phase; if (c >= 8) c -= 8;
        float xv4[4];
        #pragma unroll
        for (int it = 0; it < 4; it++)
            xv4[it] = xc[row * DI + c * PWC + it * 64 + lane];
        __syncthreads();
        #pragma unroll
        for (int ii = 0; ii < 33; ii++) {
            int i = ii + irot; if (i >= 33) i -= 33;
            s_w[i * 256 + tid] = Wx[(long)c * (PWC * 33) + i * 256 + tid];
        }
        __syncthreads();
        #pragma unroll
        for (int it = 0; it < PWC / 64; it++) {
            float xv = xv4[it];
            const float* wp = &s_w[(it * 64 + lane) * 33];
            #pragma unroll
            for (int j = 0; j < 33; j++)
                acc[j] = fmaf(xv, wp[j], acc[j]);
        }
    }
    #pragma unroll
    for (int j = 0; j < 33; j++) {
        float v = acc[j];
        v += __shfl_xor(v, 32); v += __shfl_xor(v, 16); v += __shfl_xor(v, 8);
        v += __shfl_xor(v, 4);  v += __shfl_xor(v, 2);  v += __shfl_xor(v, 1);
        if (lane == j) proj[row * PP + j] = v;
    }
}

// ---------- delta = softplus(proj[:,32]); chunk sums ----------
__global__ __launch_bounds__(256) void delta_k(const float* __restrict__ proj,
                                               float* __restrict__ delta,
                                               float* __restrict__ Dsum) {
    __shared__ float s[CL];
    const int bc = blockIdx.x;          // b*NC + c
    const int tid = threadIdx.x;
    const long row = (long)bc * CL + tid;   // == b*L + c*CL + tid
    float p = proj[row * PP + 32];
    float dv = (p > 20.f) ? p : log1pf(__expf(p));
    s[tid] = dv;
    __syncthreads();
    for (int off = 1; off < CL; off <<= 1) {
        float v = (tid >= off) ? s[tid - off] : 0.f;
        __syncthreads();
        s[tid] += v;
        __syncthreads();
    }
    delta[row] = dv;
    if (tid == CL - 1) Dsum[bc] = s[tid];
}

// ---------- pass 1: chunk-local recurrence only (h0 = 0) -> Hout. Chunks 0..6. ----------
// lane layout: n = lane&15, dq = lane>>4; d = dblk*16 + w*4 + dq
__global__ __launch_bounds__(256) void scan_part1(const float* __restrict__ xc,
                                                  const float* __restrict__ proj,
                                                  const float* __restrict__ delta,
                                                  const float* __restrict__ A_log,
                                                  float* __restrict__ Hout) {
    const int bx = blockIdx.x;          // (b*(NC-1) + c)*128 + dblk, c in 0..6
    const int dblk = bx & 127;
    const int rem = bx >> 7;
    const int b = rem / (NC - 1);
    const int c = rem - b * (NC - 1);
    const int bc = b * NC + c;
    const int tid  = threadIdx.x;
    const int w    = tid >> 6, lane = tid & 63;
    const int dq = lane >> 4, n = lane & 15;
    const int dloc = w * 4 + dq;
    const int d = dblk * 16 + dloc;

    const float A2 = -__expf(A_log[d * DS + n]) * 1.44269504088896f;
    float h = 0.f;

    __shared__ float s_B[32 * 16];
    __shared__ float s_delta[32];
    __shared__ float s_xc[32 * 16];

    const long rowbase = (long)bc * CL;
    for (int t0 = 0; t0 < CL; t0 += 32) {
        __syncthreads();
        for (int i = tid; i < 128; i += 256) {          // 32 rows x 16 cols, float4
            int r = i >> 2, cc = (i & 3) * 4;
            *(float4*)&s_B[r * 16 + cc] = *(const float4*)(proj + (rowbase + t0 + r) * PP + cc);
        }
        for (int i = tid - 128; i >= 0 && i < 128; i += 256) {
            int r = i >> 2, cc = (i & 3) * 4;
            *(float4*)&s_xc[r * 16 + cc] = *(const float4*)(xc + (rowbase + t0 + r) * DI + dblk * 16 + cc);
        }
        if (tid < 32) s_delta[tid] = delta[rowbase + t0 + tid];
        __syncthreads();
        #pragma unroll 8
        for (int r = 0; r < 32; r++) {
            float Bn = s_B[r * 16 + n];
            float dt = s_delta[r];
            float xv = s_xc[r * 16 + dloc];
            float a = __builtin_amdgcn_exp2f(dt * A2);
            h = fmaf(a, h, (dt * xv) * Bn);
        }
    }
    Hout[(long)bc * (DI * DS) + d * DS + n] = h;
}

// ---------- phase 2: sequential combine over chunks per (b,d,n) channel ----------
__global__ __launch_bounds__(256) void combine_k(const float* __restrict__ Hout,
                                                 const float* __restrict__ Dsum,
                                                 const float* __restrict__ A_log,
                                                 float* __restrict__ Hin) {
    int idx = blockIdx.x * 256 + threadIdx.x;   // 2*32768
    int b = idx >> 15;
    int rem = idx & 32767;                      // d*16+n
    const float A2 = -__expf(A_log[rem]) * 1.44269504088896f;
    float h = 0.f;
    #pragma unroll
    for (int c = 0; c < NC - 1; c++) {
        long o = (long)(b * NC + c) * (DI * DS) + rem;
        Hin[o] = h;
        h = fmaf(__builtin_amdgcn_exp2f(A2 * Dsum[b * NC + c]), h, Hout[o]);
    }
    Hin[(long)(b * NC + NC - 1) * (DI * DS) + rem] = h;
}

// ---------- pass 2: full scan with h0 = Hin, writes y once (all chunks) ----------
__global__ __launch_bounds__(256) void scan_chunk(const float* __restrict__ xc,
                                                  const float* __restrict__ proj,
                                                  const float* __restrict__ delta,
                                                  const float* __restrict__ A_log,
                                                  const float* __restrict__ Hin,
                                                  float* __restrict__ y) {
    const int bx = blockIdx.x;          // ((b*NC + c) * 128) + dblk
    const int dblk = bx & 127;
    const int bc = bx >> 7;
    const int tid  = threadIdx.x;
    const int w    = tid >> 6, lane = tid & 63;
    const int dq = lane >> 4, n = lane & 15;
    const int dloc = w * 4 + dq;
    const int d = dblk * 16 + dloc;

    const float A2 = -__expf(A_log[d * DS + n]) * 1.44269504088896f;
    float h = Hin[(long)bc * (DI * DS) + d * DS + n];

    __shared__ float s_BC[32 * 32];     // cols 0..31 of proj (B then C)
    __shared__ float s_delta[32];
    __shared__ float s_xc[32 * 16];

    const long rowbase = (long)bc * CL;
    for (int t0 = 0; t0 < CL; t0 += 32) {
        __syncthreads();
        for (int i = tid; i < 256; i += 256) {          // 32 rows x 32 cols, float4
            int r = i >> 3, cc = (i & 7) * 4;
            *(float4*)&s_BC[r * 32 + cc] = *(const float4*)(proj + (rowbase + t0 + r) * PP + cc);
        }
        for (int i = tid; i < 128; i += 256) {
            int r = i >> 2, cc = (i & 3) * 4;
            *(float4*)&s_xc[r * 16 + cc] = *(const float4*)(xc + (rowbase + t0 + r) * DI + dblk * 16 + cc);
        }
        if (tid < 32) s_delta[tid] = delta[rowbase + t0 + tid];
        __syncthreads();
        #pragma unroll 8
        for (int r = 0; r < 32; r++) {
            float Bn    = s_BC[r * 32 + n];
            float Cn    = s_BC[r * 32 + 16 + n];
            float dt    = s_delta[r];
            float xv    = s_xc[r * 16 + dloc];
            float a = __builtin_amdgcn_exp2f(dt * A2);
            h = fmaf(a, h, (dt * xv) * Bn);
            float p = h * Cn;
            p += dpp_shr<0x111>(p);
            p += dpp_shr<0x112>(p);
            p += dpp_shr<0x114>(p);
            p += dpp_shr<0x118>(p);
            if (n == 15) y[(rowbase + t0 + r) * DI + d] = p;
        }
    }
}

// ---------- final elementwise: ybf = bf16((y + xc*D) * silu(z)) ----------
__global__ __launch_bounds__(256) void final_ew(const float* __restrict__ y,
                                                const float* __restrict__ xc,
                                                const float* __restrict__ xz,
                                                const float* __restrict__ Dp,
                                                short* __restrict__ ybf) {
    int idx = blockIdx.x * 256 + threadIdx.x;   // 4096 rows * 512 d-groups
    int dg = idx & 511;
    long row = idx >> 9;
    int d = dg * 4;
    float4 yv  = *(const float4*)(y  + row * DI + d);
    float4 xcv = *(const float4*)(xc + row * DI + d);
    float4 zv  = *(const float4*)(xz + row * 4096 + DI + d);
    float4 dv  = *(const float4*)(Dp + d);
    short4v o;
    float v;
    v = (yv.x + xcv.x * dv.x) * (zv.x / (1.f + __expf(-zv.x))); o.x = f2bf(v);
    v = (yv.y + xcv.y * dv.y) * (zv.y / (1.f + __expf(-zv.y))); o.y = f2bf(v);
    v = (yv.z + xcv.z * dv.z) * (zv.z / (1.f + __expf(-zv.z))); o.z = f2bf(v);
    v = (yv.w + xcv.w * dv.w) * (zv.w / (1.f + __expf(-zv.w))); o.w = f2bf(v);
    *(short4v*)(ybf + row * DI + d) = o;
}

// ---------- launch ----------
extern "C" void kernel_launch(void* const* d_in, const int* in_sizes, int n_in,
                              void* d_out, int out_size, void* d_ws, size_t ws_size,
                              hipStream_t stream) {
    const float* x      = (const float*)d_in[0];
    const float* W_in   = (const float*)d_in[1];
    const float* b_in   = (const float*)d_in[2];
    const float* conv_w = (const float*)d_in[3];
    const float* conv_b = (const float*)d_in[4];
    const float* W_xprj = (const float*)d_in[5];
    const float* A_log  = (const float*)d_in[6];
    const float* D_par  = (const float*)d_in[7];
    const float* W_out  = (const float*)d_in[8];
    const float* b_out  = (const float*)d_in[9];
    float* out = (float*)d_out;
    char* ws = (char*)d_ws;

    // workspace layout (bytes) — high-water ~154.4 MB (unchanged)
    const size_t OFF_XBF  = 0;              // 8 MB (dead after gemm1)
    const size_t OFF_WINT = 8388608;        // 8 MB (dead after gemm1)
    const size_t OFF_HOUT = 0;              // 2 MB, overlays dead xbf
    const size_t OFF_HIN  = 2097152;        // 2 MB
    const size_t OFF_YBF  = 0;              // 16 MB, written by final_ew
    const size_t OFF_WOT  = 16777216;       // 4 MB
    const size_t OFF_DELTA= 20971520;       // 16 KB
    const size_t OFF_DSUM = 21004288;       // 64 B
    const size_t OFF_XZ   = 21241856;       // 64 MB
    const size_t OFF_XC   = 88350720;       // 32 MB
    const size_t OFF_PROJ = 121905152;      // 4096*36*4 = 590 KB
    const size_t OFF_Y    = 122945536;      // 32 MB

    short* xbf  = (short*)(ws + OFF_XBF);
    short* WinT = (short*)(ws + OFF_WINT);
    short* ybf  = (short*)(ws + OFF_YBF);
    short* WoT  = (short*)(ws + OFF_WOT);
    float* Hout = (float*)(ws + OFF_HOUT);
    float* Hin  = (float*)(ws + OFF_HIN);
    float* delta= (float*)(ws + OFF_DELTA);
    float* Dsum = (float*)(ws + OFF_DSUM);
    float* xz   = (float*)(ws + OFF_XZ);
    float* xc   = (float*)(ws + OFF_XC);
    float* proj = (float*)(ws + OFF_PROJ);
    float* y    = (float*)(ws + OFF_Y);

    convert_x_k<<<4096, 256, 0, stream>>>(x, xbf);
    transpose_to_bf16<<<dim3(128, 32), 256, 0, stream>>>(W_in, WinT, 1024, 4096);
    transpose_to_bf16<<<dim3(32, 64), 256, 0, stream>>>(W_out, WoT, 2048, 1024);

    gemm_bt<<<dim3(32, 32), 256, 0, stream>>>(xbf, WinT, xz, b_in, NROW, 4096, 1024);
    conv_silu_k<<<8192, 256, 0, stream>>>(xz, conv_w, conv_b, xc);
    proj_gemm<<<1024, 256, 0, stream>>>(xc, W_xprj, proj);
    delta_k<<<B_SZ * NC, 256, 0, stream>>>(proj, delta, Dsum);
    scan_part1<<<B_SZ * (NC - 1) * 128, 256, 0, stream>>>(xc, proj, delta, A_log, Hout);
    combine_k<<<256, 256, 0, stream>>>(Hout, Dsum, A_log, Hin);
    scan_chunk<<<B_SZ * NC * 128, 256, 0, stream>>>(xc, proj, delta, A_log, Hin, y);
    final_ew<<<8192, 256, 0, stream>>>(y, xc, xz, D_par, ybf);
    gemm_bt<<<dim3(8, 32), 256, 0, stream>>>(ybf, WoT, out, b_out, NROW, 1024, 2048);
}

// Round 9
// 433.506 us; speedup vs baseline: 1.0003x; 1.0003x over previous
//
#include <hip/hip_runtime.h>
#include <stdint.h>

// ---------- types ----------
typedef __attribute__((ext_vector_type(8))) short short8;   // 8 bf16 (4 VGPRs)
typedef __attribute__((ext_vector_type(4))) short short4v;
typedef __attribute__((ext_vector_type(4))) float f32x4;

typedef __attribute__((address_space(1))) void as1_void;
typedef __attribute__((address_space(3))) void as3_void;

#define B_SZ 2
#define L_SZ 2048
#define DM   1024
#define DI   2048
#define DS   16
#define NROW 4096          // B_SZ * L_SZ
#define NC   8             // scan chunks
#define CL   256           // chunk length
#define PP   36            // proj row pitch (padded from 33 for aligned float4)

__device__ __forceinline__ short f2bf(float f) {
    unsigned u = __float_as_uint(f);
    u += 0x7FFF + ((u >> 16) & 1);           // RNE
    return (short)(u >> 16);
}

__device__ __forceinline__ void gl2lds16(const void* g, void* l) {
    __builtin_amdgcn_global_load_lds((as1_void*)(void*)(uintptr_t)(const_cast<void*>(g)),
                                     (as3_void*)l, 16, 0, 0);
}

template<int CTRL>
__device__ __forceinline__ float dpp_shr(float x) {
    int i = __float_as_int(x);
    i = __builtin_amdgcn_update_dpp(0, i, CTRL, 0xF, 0xF, true);
    return __int_as_float(i);
}

// ---------- convert x -> bf16 ----------
__global__ __launch_bounds__(256) void convert_x_k(const float* __restrict__ x,
                                                   short* __restrict__ xbf) {
    int idx = blockIdx.x * 256 + threadIdx.x;      // over 4M/4 groups
    float4 v = ((const float4*)x)[idx];
    short4v o;
    o.x = f2bf(v.x); o.y = f2bf(v.y); o.z = f2bf(v.z); o.w = f2bf(v.w);
    ((short4v*)xbf)[idx] = o;
}

// ---------- transpose KxN fp32 -> NxK bf16 ----------
__global__ __launch_bounds__(256) void transpose_to_bf16(const float* __restrict__ in,
                                                         short* __restrict__ out,
                                                         int K, int N) {
    __shared__ float tile[32][33];
    int tx = threadIdx.x & 31, ty = threadIdx.x >> 5;   // 32 x 8
    int n0 = blockIdx.x * 32, k0 = blockIdx.y * 32;
    #pragma unroll
    for (int i = 0; i < 4; i++) {
        int r = ty + i * 8;
        tile[r][tx] = in[(long)(k0 + r) * N + n0 + tx];
    }
    __syncthreads();
    #pragma unroll
    for (int i = 0; i < 4; i++) {
        int r = ty + i * 8;
        out[(long)(n0 + r) * K + k0 + tx] = f2bf(tile[tx][r]);
    }
}

// ---------- bf16 MFMA GEMM:  C(MxN) = A(MxK,lda) * BT(NxK,ldb)^T + bias ----------
// R8 post-mortem: K-phase rotation destroyed L2 panel reuse (FETCH 41->283 MB).
// Reverted to the R6 form (lockstep = L2 temporal reuse, a feature not a bug).
// lda/ldb added so GEMM3 can read ybf embedded in xz rows (stride 8192).
#define BM 128
#define BN 128
#define BK 32
__global__ __launch_bounds__(256) void gemm_bt(const short* __restrict__ A, int lda,
                                               const short* __restrict__ BT, int ldb,
                                               float* __restrict__ C,
                                               const float* __restrict__ bias,
                                               int M, int N, int K) {
    __shared__ __align__(16) short As[BM * BK];   // 8 KB
    __shared__ __align__(16) short Bs[BN * BK];   // 8 KB
    const int tid  = threadIdx.x;
    const int w    = tid >> 6;
    const int lane = tid & 63;
    const int bm = blockIdx.y * BM, bn = blockIdx.x * BN;
    const int wm = (w & 1) * 64, wn = (w >> 1) * 64;
    const int quad = lane >> 4, r16 = lane & 15;

    const int srow = w * 16 + (lane >> 2);
    const int scol = (lane & 3) * 8;
    const short* Ag = A  + (long)(bm + srow) * lda + scol;
    const short* Bg = BT + (long)(bn + srow) * ldb + scol;
    char* AsB = (char*)As + w * 1024;
    char* BsB = (char*)Bs + w * 1024;

    f32x4 acc[4][4] = {};
    for (int k0 = 0; k0 < K; k0 += BK) {
        __syncthreads();
        gl2lds16(Ag + k0,                    AsB);
        gl2lds16(Ag + (long)64 * lda + k0,   AsB + 4096);
        gl2lds16(Bg + k0,                    BsB);
        gl2lds16(Bg + (long)64 * ldb + k0,   BsB + 4096);
        __syncthreads();

        short8 af[4], bfr[4];
        #pragma unroll
        for (int i = 0; i < 4; i++)
            af[i] = *(const short8*)&As[(wm + i * 16 + r16) * BK + quad * 8];
        #pragma unroll
        for (int j = 0; j < 4; j++)
            bfr[j] = *(const short8*)&Bs[(wn + j * 16 + r16) * BK + quad * 8];
        #pragma unroll
        for (int i = 0; i < 4; i++)
            #pragma unroll
            for (int j = 0; j < 4; j++)
                acc[i][j] = __builtin_amdgcn_mfma_f32_16x16x32_bf16(af[i], bfr[j], acc[i][j], 0, 0, 0);
    }
    #pragma unroll
    for (int i = 0; i < 4; i++) {
        #pragma unroll
        for (int j = 0; j < 4; j++) {
            int col = bn + wn + j * 16 + r16;
            float bv = bias[col];
            #pragma unroll
            for (int r = 0; r < 4; r++) {
                int row = bm + wm + i * 16 + quad * 4 + r;
                C[(long)row * N + col] = acc[i][j][r] + bv;
            }
        }
    }
}

// ---------- depthwise causal conv (k=4) + SiLU ----------
__global__ __launch_bounds__(256) void conv_silu_k(const float* __restrict__ xz,
                                                   const float* __restrict__ cw,
                                                   const float* __restrict__ cb,
                                                   float* __restrict__ xc) {
    int idx = blockIdx.x * 256 + threadIdx.x;    // 4096 rows * 512 d-groups
    int dg = idx & 511;
    int row = idx >> 9;
    int t = row & (L_SZ - 1);
    int d = dg * 4;
    float4 acc = *(const float4*)(cb + d);
    float4 c0 = *(const float4*)(cw + (d + 0) * 4);
    float4 c1 = *(const float4*)(cw + (d + 1) * 4);
    float4 c2 = *(const float4*)(cw + (d + 2) * 4);
    float4 c3 = *(const float4*)(cw + (d + 3) * 4);
    const float cw0[4] = {c0.x, c0.y, c0.z, c0.w};
    const float cw1[4] = {c1.x, c1.y, c1.z, c1.w};
    const float cw2[4] = {c2.x, c2.y, c2.z, c2.w};
    const float cw3[4] = {c3.x, c3.y, c3.z, c3.w};
    #pragma unroll
    for (int k = 0; k < 4; k++) {
        int tt = t - 3 + k;
        if (tt >= 0) {
            float4 xv = *(const float4*)(xz + (long)(row - 3 + k) * 4096 + d);
            acc.x += xv.x * cw0[k];
            acc.y += xv.y * cw1[k];
            acc.z += xv.z * cw2[k];
            acc.w += xv.w * cw3[k];
        }
    }
    float4 o;
    o.x = acc.x / (1.f + __expf(-acc.x));
    o.y = acc.y / (1.f + __expf(-acc.y));
    o.z = acc.z / (1.f + __expf(-acc.z));
    o.w = acc.w / (1.f + __expf(-acc.w));
    *(float4*)(xc + (long)row * DI + d) = o;
}

// ---------- proj = xc @ W_xproj  (wave per row; Wx chunks staged in LDS) ----------
// Decorrelated chunk/staging order per block (R5 win: 270 KB stream, no capacity reuse).
#define PWC 256            // k-chunk staged per iteration
__global__ __launch_bounds__(256) void proj_gemm(const float* __restrict__ xc,
                                                 const float* __restrict__ Wx,
                                                 float* __restrict__ proj) {
    __shared__ float s_w[PWC * 33];            // 33.8 KB
    const int tid = threadIdx.x;
    const int w = tid >> 6, lane = tid & 63;
    const int bx = blockIdx.x;
    const long row = (long)bx * 4 + w;
    const int phase = (bx >> 3) & 7;           // chunk-order stagger
    const int irot  = (bx * 7) & 31;           // staging-order rotation (<33)

    float acc[33];
    #pragma unroll
    for (int j = 0; j < 33; j++) acc[j] = 0.f;

    for (int cc = 0; cc < DI / PWC; cc++) {
        int c = cc + phase; if (c >= 8) c -= 8;
        float xv4[4];
        #pragma unroll
        for (int it = 0; it < 4; it++)
            xv4[it] = xc[row * DI + c * PWC + it * 64 + lane];
        __syncthreads();
        #pragma unroll
        for (int ii = 0; ii < 33; ii++) {
            int i = ii + irot; if (i >= 33) i -= 33;
            s_w[i * 256 + tid] = Wx[(long)c * (PWC * 33) + i * 256 + tid];
        }
        __syncthreads();
        #pragma unroll
        for (int it = 0; it < PWC / 64; it++) {
            float xv = xv4[it];
            const float* wp = &s_w[(it * 64 + lane) * 33];
            #pragma unroll
            for (int j = 0; j < 33; j++)
                acc[j] = fmaf(xv, wp[j], acc[j]);
        }
    }
    #pragma unroll
    for (int j = 0; j < 33; j++) {
        float v = acc[j];
        v += __shfl_xor(v, 32); v += __shfl_xor(v, 16); v += __shfl_xor(v, 8);
        v += __shfl_xor(v, 4);  v += __shfl_xor(v, 2);  v += __shfl_xor(v, 1);
        if (lane == j) proj[row * PP + j] = v;
    }
}

// ---------- delta = softplus(proj[:,32]); chunk sums ----------
__global__ __launch_bounds__(256) void delta_k(const float* __restrict__ proj,
                                               float* __restrict__ delta,
                                               float* __restrict__ Dsum) {
    __shared__ float s[CL];
    const int bc = blockIdx.x;          // b*NC + c
    const int tid = threadIdx.x;
    const long row = (long)bc * CL + tid;   // == b*L + c*CL + tid
    float p = proj[row * PP + 32];
    float dv = (p > 20.f) ? p : log1pf(__expf(p));
    s[tid] = dv;
    __syncthreads();
    for (int off = 1; off < CL; off <<= 1) {
        float v = (tid >= off) ? s[tid - off] : 0.f;
        __syncthreads();
        s[tid] += v;
        __syncthreads();
    }
    delta[row] = dv;
    if (tid == CL - 1) Dsum[bc] = s[tid];
}

// ---------- pass 1: chunk-local recurrence only (h0 = 0) -> Hout. Chunks 0..6. ----------
// lane layout: n = lane&15, dq = lane>>4; d = dblk*16 + w*4 + dq
__global__ __launch_bounds__(256) void scan_part1(const float* __restrict__ xc,
                                                  const float* __restrict__ proj,
                                                  const float* __restrict__ delta,
                                                  const float* __restrict__ A_log,
                                                  float* __restrict__ Hout) {
    const int bx = blockIdx.x;          // (b*(NC-1) + c)*128 + dblk, c in 0..6
    const int dblk = bx & 127;
    const int rem = bx >> 7;
    const int b = rem / (NC - 1);
    const int c = rem - b * (NC - 1);
    const int bc = b * NC + c;
    const int tid  = threadIdx.x;
    const int w    = tid >> 6, lane = tid & 63;
    const int dq = lane >> 4, n = lane & 15;
    const int dloc = w * 4 + dq;
    const int d = dblk * 16 + dloc;

    const float A2 = -__expf(A_log[d * DS + n]) * 1.44269504088896f;
    float h = 0.f;

    __shared__ float s_B[32 * 16];
    __shared__ float s_delta[32];
    __shared__ float s_xc[32 * 16];

    const long rowbase = (long)bc * CL;
    for (int t0 = 0; t0 < CL; t0 += 32) {
        __syncthreads();
        for (int i = tid; i < 128; i += 256) {          // 32 rows x 16 cols, float4
            int r = i >> 2, cc = (i & 3) * 4;
            *(float4*)&s_B[r * 16 + cc] = *(const float4*)(proj + (rowbase + t0 + r) * PP + cc);
        }
        for (int i = tid - 128; i >= 0 && i < 128; i += 256) {
            int r = i >> 2, cc = (i & 3) * 4;
            *(float4*)&s_xc[r * 16 + cc] = *(const float4*)(xc + (rowbase + t0 + r) * DI + dblk * 16 + cc);
        }
        if (tid < 32) s_delta[tid] = delta[rowbase + t0 + tid];
        __syncthreads();
        #pragma unroll 8
        for (int r = 0; r < 32; r++) {
            float Bn = s_B[r * 16 + n];
            float dt = s_delta[r];
            float xv = s_xc[r * 16 + dloc];
            float a = __builtin_amdgcn_exp2f(dt * A2);
            h = fmaf(a, h, (dt * xv) * Bn);
        }
    }
    Hout[(long)bc * (DI * DS) + d * DS + n] = h;
}

// ---------- phase 2: sequential combine over chunks per (b,d,n) channel ----------
__global__ __launch_bounds__(256) void combine_k(const float* __restrict__ Hout,
                                                 const float* __restrict__ Dsum,
                                                 const float* __restrict__ A_log,
                                                 float* __restrict__ Hin) {
    int idx = blockIdx.x * 256 + threadIdx.x;   // 2*32768
    int b = idx >> 15;
    int rem = idx & 32767;                      // d*16+n
    const float A2 = -__expf(A_log[rem]) * 1.44269504088896f;
    float h = 0.f;
    #pragma unroll
    for (int c = 0; c < NC - 1; c++) {
        long o = (long)(b * NC + c) * (DI * DS) + rem;
        Hin[o] = h;
        h = fmaf(__builtin_amdgcn_exp2f(A2 * Dsum[b * NC + c]), h, Hout[o]);
    }
    Hin[(long)(b * NC + NC - 1) * (DI * DS) + rem] = h;
}

// ---------- pass 2: full scan with h0 = Hin, fused epilogue ----------
// Writes ybf = bf16((y + xc*D) * silu(z)) directly into the dead x_ssm half of
// each xz row (bf16, row stride 8192 shorts). Eliminates y buffer + final_ew.
__global__ __launch_bounds__(256) void scan_chunk(const float* __restrict__ xc,
                                                  const float* __restrict__ proj,
                                                  const float* __restrict__ delta,
                                                  const float* __restrict__ A_log,
                                                  const float* __restrict__ Hin,
                                                  const float* __restrict__ xz,
                                                  const float* __restrict__ Dp,
                                                  short* __restrict__ ybf) {
    const int bx = blockIdx.x;          // ((b*NC + c) * 128) + dblk
    const int dblk = bx & 127;
    const int bc = bx >> 7;
    const int tid  = threadIdx.x;
    const int w    = tid >> 6, lane = tid & 63;
    const int dq = lane >> 4, n = lane & 15;
    const int dloc = w * 4 + dq;
    const int d = dblk * 16 + dloc;

    const float A2 = -__expf(A_log[d * DS + n]) * 1.44269504088896f;
    float h = Hin[(long)bc * (DI * DS) + d * DS + n];
    const float Dv = Dp[d];

    __shared__ float s_BC[32 * 32];     // cols 0..31 of proj (B then C)
    __shared__ float s_delta[32];
    __shared__ float s_xc[32 * 16];
    __shared__ float s_z[32 * 16];

    const long rowbase = (long)bc * CL;
    for (int t0 = 0; t0 < CL; t0 += 32) {
        __syncthreads();
        for (int i = tid; i < 256; i += 256) {          // 32 rows x 32 cols, float4
            int r = i >> 3, cc = (i & 7) * 4;
            *(float4*)&s_BC[r * 32 + cc] = *(const float4*)(proj + (rowbase + t0 + r) * PP + cc);
        }
        for (int i = tid; i < 128; i += 256) {
            int r = i >> 2, cc = (i & 3) * 4;
            *(float4*)&s_xc[r * 16 + cc] = *(const float4*)(xc + (rowbase + t0 + r) * DI + dblk * 16 + cc);
            *(float4*)&s_z[r * 16 + cc]  = *(const float4*)(xz + (rowbase + t0 + r) * 4096 + DI + dblk * 16 + cc);
        }
        if (tid < 32) s_delta[tid] = delta[rowbase + t0 + tid];
        __syncthreads();
        #pragma unroll 8
        for (int r = 0; r < 32; r++) {
            float Bn    = s_BC[r * 32 + n];
            float Cn    = s_BC[r * 32 + 16 + n];
            float dt    = s_delta[r];
            float xv    = s_xc[r * 16 + dloc];
            float a = __builtin_amdgcn_exp2f(dt * A2);
            h = fmaf(a, h, (dt * xv) * Bn);
            float p = h * Cn;
            p += dpp_shr<0x111>(p);
            p += dpp_shr<0x112>(p);
            p += dpp_shr<0x114>(p);
            p += dpp_shr<0x118>(p);
            if (n == 15) {
                float zv = s_z[r * 16 + dloc];
                float val = (p + xv * Dv) * (zv / (1.f + __expf(-zv)));
                ybf[(rowbase + t0 + r) * 8192 + d] = f2bf(val);
            }
        }
    }
}

// ---------- launch ----------
extern "C" void kernel_launch(void* const* d_in, const int* in_sizes, int n_in,
                              void* d_out, int out_size, void* d_ws, size_t ws_size,
                              hipStream_t stream) {
    const float* x      = (const float*)d_in[0];
    const float* W_in   = (const float*)d_in[1];
    const float* b_in   = (const float*)d_in[2];
    const float* conv_w = (const float*)d_in[3];
    const float* conv_b = (const float*)d_in[4];
    const float* W_xprj = (const float*)d_in[5];
    const float* A_log  = (const float*)d_in[6];
    const float* D_par  = (const float*)d_in[7];
    const float* W_out  = (const float*)d_in[8];
    const float* b_out  = (const float*)d_in[9];
    float* out = (float*)d_out;
    char* ws = (char*)d_ws;

    // workspace layout (bytes) — high-water ~122.5 MB (y buffer removed)
    const size_t OFF_XBF  = 0;              // 8 MB (dead after gemm1)
    const size_t OFF_WINT = 8388608;        // 8 MB (dead after gemm1)
    const size_t OFF_HOUT = 0;              // 2 MB, overlays dead xbf
    const size_t OFF_HIN  = 2097152;        // 2 MB
    const size_t OFF_WOT  = 16777216;       // 4 MB
    const size_t OFF_DELTA= 20971520;       // 16 KB
    const size_t OFF_DSUM = 21004288;       // 64 B
    const size_t OFF_XZ   = 21241856;       // 64 MB (x_ssm half becomes ybf)
    const size_t OFF_XC   = 88350720;       // 32 MB
    const size_t OFF_PROJ = 121905152;      // 4096*36*4 = 590 KB

    short* xbf  = (short*)(ws + OFF_XBF);
    short* WinT = (short*)(ws + OFF_WINT);
    short* WoT  = (short*)(ws + OFF_WOT);
    float* Hout = (float*)(ws + OFF_HOUT);
    float* Hin  = (float*)(ws + OFF_HIN);
    float* delta= (float*)(ws + OFF_DELTA);
    float* Dsum = (float*)(ws + OFF_DSUM);
    float* xz   = (float*)(ws + OFF_XZ);
    float* xc   = (float*)(ws + OFF_XC);
    float* proj = (float*)(ws + OFF_PROJ);
    short* ybf  = (short*)(ws + OFF_XZ);    // bf16, row stride 8192 (x_ssm half of xz)

    convert_x_k<<<4096, 256, 0, stream>>>(x, xbf);
    transpose_to_bf16<<<dim3(128, 32), 256, 0, stream>>>(W_in, WinT, 1024, 4096);
    transpose_to_bf16<<<dim3(32, 64), 256, 0, stream>>>(W_out, WoT, 2048, 1024);

    gemm_bt<<<dim3(32, 32), 256, 0, stream>>>(xbf, 1024, WinT, 1024, xz, b_in, NROW, 4096, 1024);
    conv_silu_k<<<8192, 256, 0, stream>>>(xz, conv_w, conv_b, xc);
    proj_gemm<<<1024, 256, 0, stream>>>(xc, W_xprj, proj);
    delta_k<<<B_SZ * NC, 256, 0, stream>>>(proj, delta, Dsum);
    scan_part1<<<B_SZ * (NC - 1) * 128, 256, 0, stream>>>(xc, proj, delta, A_log, Hout);
    combine_k<<<256, 256, 0, stream>>>(Hout, Dsum, A_log, Hin);
    scan_chunk<<<B_SZ * NC * 128, 256, 0, stream>>>(xc, proj, delta, A_log, Hin, xz, D_par, ybf);
    gemm_bt<<<dim3(8, 32), 256, 0, stream>>>(ybf, 8192, WoT, 2048, out, b_out, NROW, 1024, 2048);
}

// Round 11
// 374.757 us; speedup vs baseline: 1.1571x; 1.1568x over previous
//
#include <hip/hip_runtime.h>
#include <stdint.h>

// ---------- types ----------
typedef __attribute__((ext_vector_type(8))) short short8;   // 8 bf16 (4 VGPRs)
typedef __attribute__((ext_vector_type(4))) short short4v;
typedef __attribute__((ext_vector_type(4))) float f32x4;

typedef __attribute__((address_space(1))) void as1_void;
typedef __attribute__((address_space(3))) void as3_void;

#define B_SZ 2
#define L_SZ 2048
#define DM   1024
#define DI   2048
#define DS   16
#define NROW 4096          // B_SZ * L_SZ
#define NC   8             // scan chunks
#define CL   256           // chunk length
#define PP   36            // proj row pitch (padded from 33 for aligned float4)

__device__ __forceinline__ short f2bf(float f) {
    unsigned u = __float_as_uint(f);
    u += 0x7FFF + ((u >> 16) & 1);           // RNE
    return (short)(u >> 16);
}

__device__ __forceinline__ void gl2lds16(const void* g, void* l) {
    __builtin_amdgcn_global_load_lds((as1_void*)(void*)(uintptr_t)(const_cast<void*>(g)),
                                     (as3_void*)l, 16, 0, 0);
}

template<int CTRL>
__device__ __forceinline__ float dpp_shr(float x) {
    int i = __float_as_int(x);
    i = __builtin_amdgcn_update_dpp(0, i, CTRL, 0xF, 0xF, true);
    return __int_as_float(i);
}

// ---------- convert x -> bf16 ----------
__global__ __launch_bounds__(256) void convert_x_k(const float* __restrict__ x,
                                                   short* __restrict__ xbf) {
    int idx = blockIdx.x * 256 + threadIdx.x;      // over 4M/4 groups
    float4 v = ((const float4*)x)[idx];
    short4v o;
    o.x = f2bf(v.x); o.y = f2bf(v.y); o.z = f2bf(v.z); o.w = f2bf(v.w);
    ((short4v*)xbf)[idx] = o;
}

// ---------- transpose KxN fp32 -> NxK bf16 ----------
__global__ __launch_bounds__(256) void transpose_to_bf16(const float* __restrict__ in,
                                                         short* __restrict__ out,
                                                         int K, int N) {
    __shared__ float tile[32][33];
    int tx = threadIdx.x & 31, ty = threadIdx.x >> 5;   // 32 x 8
    int n0 = blockIdx.x * 32, k0 = blockIdx.y * 32;
    #pragma unroll
    for (int i = 0; i < 4; i++) {
        int r = ty + i * 8;
        tile[r][tx] = in[(long)(k0 + r) * N + n0 + tx];
    }
    __syncthreads();
    #pragma unroll
    for (int i = 0; i < 4; i++) {
        int r = ty + i * 8;
        out[(long)(n0 + r) * K + k0 + tx] = f2bf(tile[tx][r]);
    }
}

// ---------- bf16 MFMA GEMM:  C(MxN) = A(MxK,lda) * BT(NxK,ldb)^T + bias ----------
// R8 lesson: lockstep panel reads = L2 temporal reuse (feature, not bug). No remap.
#define BM 128
#define BN 128
#define BK 32
__global__ __launch_bounds__(256) void gemm_bt(const short* __restrict__ A, int lda,
                                               const short* __restrict__ BT, int ldb,
                                               float* __restrict__ C,
                                               const float* __restrict__ bias,
                                               int M, int N, int K) {
    __shared__ __align__(16) short As[BM * BK];   // 8 KB
    __shared__ __align__(16) short Bs[BN * BK];   // 8 KB
    const int tid  = threadIdx.x;
    const int w    = tid >> 6;
    const int lane = tid & 63;
    const int bm = blockIdx.y * BM, bn = blockIdx.x * BN;
    const int wm = (w & 1) * 64, wn = (w >> 1) * 64;
    const int quad = lane >> 4, r16 = lane & 15;

    const int srow = w * 16 + (lane >> 2);
    const int scol = (lane & 3) * 8;
    const short* Ag = A  + (long)(bm + srow) * lda + scol;
    const short* Bg = BT + (long)(bn + srow) * ldb + scol;
    char* AsB = (char*)As + w * 1024;
    char* BsB = (char*)Bs + w * 1024;

    f32x4 acc[4][4] = {};
    for (int k0 = 0; k0 < K; k0 += BK) {
        __syncthreads();
        gl2lds16(Ag + k0,                    AsB);
        gl2lds16(Ag + (long)64 * lda + k0,   AsB + 4096);
        gl2lds16(Bg + k0,                    BsB);
        gl2lds16(Bg + (long)64 * ldb + k0,   BsB + 4096);
        __syncthreads();

        short8 af[4], bfr[4];
        #pragma unroll
        for (int i = 0; i < 4; i++)
            af[i] = *(const short8*)&As[(wm + i * 16 + r16) * BK + quad * 8];
        #pragma unroll
        for (int j = 0; j < 4; j++)
            bfr[j] = *(const short8*)&Bs[(wn + j * 16 + r16) * BK + quad * 8];
        #pragma unroll
        for (int i = 0; i < 4; i++)
            #pragma unroll
            for (int j = 0; j < 4; j++)
                acc[i][j] = __builtin_amdgcn_mfma_f32_16x16x32_bf16(af[i], bfr[j], acc[i][j], 0, 0, 0);
    }
    #pragma unroll
    for (int i = 0; i < 4; i++) {
        #pragma unroll
        for (int j = 0; j < 4; j++) {
            int col = bn + wn + j * 16 + r16;
            float bv = bias[col];
            #pragma unroll
            for (int r = 0; r < 4; r++) {
                int row = bm + wm + i * 16 + quad * 4 + r;
                C[(long)row * N + col] = acc[i][j][r] + bv;
            }
        }
    }
}

// ---------- depthwise causal conv (k=4) + SiLU ----------
__global__ __launch_bounds__(256) void conv_silu_k(const float* __restrict__ xz,
                                                   const float* __restrict__ cw,
                                                   const float* __restrict__ cb,
                                                   float* __restrict__ xc) {
    int idx = blockIdx.x * 256 + threadIdx.x;    // 4096 rows * 512 d-groups
    int dg = idx & 511;
    int row = idx >> 9;
    int t = row & (L_SZ - 1);
    int d = dg * 4;
    float4 acc = *(const float4*)(cb + d);
    float4 c0 = *(const float4*)(cw + (d + 0) * 4);
    float4 c1 = *(const float4*)(cw + (d + 1) * 4);
    float4 c2 = *(const float4*)(cw + (d + 2) * 4);
    float4 c3 = *(const float4*)(cw + (d + 3) * 4);
    const float cw0[4] = {c0.x, c0.y, c0.z, c0.w};
    const float cw1[4] = {c1.x, c1.y, c1.z, c1.w};
    const float cw2[4] = {c2.x, c2.y, c2.z, c2.w};
    const float cw3[4] = {c3.x, c3.y, c3.z, c3.w};
    #pragma unroll
    for (int k = 0; k < 4; k++) {
        int tt = t - 3 + k;
        if (tt >= 0) {
            float4 xv = *(const float4*)(xz + (long)(row - 3 + k) * 4096 + d);
            acc.x += xv.x * cw0[k];
            acc.y += xv.y * cw1[k];
            acc.z += xv.z * cw2[k];
            acc.w += xv.w * cw3[k];
        }
    }
    float4 o;
    o.x = acc.x / (1.f + __expf(-acc.x));
    o.y = acc.y / (1.f + __expf(-acc.y));
    o.z = acc.z / (1.f + __expf(-acc.z));
    o.w = acc.w / (1.f + __expf(-acc.w));
    *(float4*)(xc + (long)row * DI + d) = o;
}

// ---------- proj = xc @ W_xproj  (wave per row; Wx chunks staged in LDS) ----------
// Decorrelated chunk/staging order per block (R5 win: 270 KB stream, no capacity reuse).
#define PWC 256            // k-chunk staged per iteration
__global__ __launch_bounds__(256) void proj_gemm(const float* __restrict__ xc,
                                                 const float* __restrict__ Wx,
                                                 float* __restrict__ proj) {
    __shared__ float s_w[PWC * 33];            // 33.8 KB
    const int tid = threadIdx.x;
    const int w = tid >> 6, lane = tid & 63;
    const int bx = blockIdx.x;
    const long row = (long)bx * 4 + w;
    const int phase = (bx >> 3) & 7;           // chunk-order stagger
    const int irot  = (bx * 7) & 31;           // staging-order rotation (<33)

    float acc[33];
    #pragma unroll
    for (int j = 0; j < 33; j++) acc[j] = 0.f;

    for (int cc = 0; cc < DI / PWC; cc++) {
        int c = cc + phase; if (c >= 8) c -= 8;
        float xv4[4];
        #pragma unroll
        for (int it = 0; it < 4; it++)
            xv4[it] = xc[row * DI + c * PWC + it * 64 + lane];
        __syncthreads();
        #pragma unroll
        for (int ii = 0; ii < 33; ii++) {
            int i = ii + irot; if (i >= 33) i -= 33;
            s_w[i * 256 + tid] = Wx[(long)c * (PWC * 33) + i * 256 + tid];
        }
        __syncthreads();
        #pragma unroll
        for (int it = 0; it < PWC / 64; it++) {
            float xv = xv4[it];
            const float* wp = &s_w[(it * 64 + lane) * 33];
            #pragma unroll
            for (int j = 0; j < 33; j++)
                acc[j] = fmaf(xv, wp[j], acc[j]);
        }
    }
    #pragma unroll
    for (int j = 0; j < 33; j++) {
        float v = acc[j];
        v += __shfl_xor(v, 32); v += __shfl_xor(v, 16); v += __shfl_xor(v, 8);
        v += __shfl_xor(v, 4);  v += __shfl_xor(v, 2);  v += __shfl_xor(v, 1);
        if (lane == j) proj[row * PP + j] = v;
    }
}

// ---------- delta = softplus(proj[:,32]); chunk sums ----------
__global__ __launch_bounds__(256) void delta_k(const float* __restrict__ proj,
                                               float* __restrict__ delta,
                                               float* __restrict__ Dsum) {
    __shared__ float s[CL];
    const int bc = blockIdx.x;          // b*NC + c
    const int tid = threadIdx.x;
    const long row = (long)bc * CL + tid;   // == b*L + c*CL + tid
    float p = proj[row * PP + 32];
    float dv = (p > 20.f) ? p : log1pf(__expf(p));
    s[tid] = dv;
    __syncthreads();
    for (int off = 1; off < CL; off <<= 1) {
        float v = (tid >= off) ? s[tid - off] : 0.f;
        __syncthreads();
        s[tid] += v;
        __syncthreads();
    }
    delta[row] = dv;
    if (tid == CL - 1) Dsum[bc] = s[tid];
}

// ---------- pass 1: chunk-local recurrence only (h0 = 0) -> Hout. Chunks 0..6. ----------
// lane layout: n = lane&15, dq = lane>>4; d = dblk*16 + w*4 + dq
__global__ __launch_bounds__(256) void scan_part1(const float* __restrict__ xc,
                                                  const float* __restrict__ proj,
                                                  const float* __restrict__ delta,
                                                  const float* __restrict__ A_log,
                                                  float* __restrict__ Hout) {
    const int bx = blockIdx.x;          // (b*(NC-1) + c)*128 + dblk, c in 0..6
    const int dblk = bx & 127;
    const int rem = bx >> 7;
    const int b = rem / (NC - 1);
    const int c = rem - b * (NC - 1);
    const int bc = b * NC + c;
    const int tid  = threadIdx.x;
    const int w    = tid >> 6, lane = tid & 63;
    const int dq = lane >> 4, n = lane & 15;
    const int dloc = w * 4 + dq;
    const int d = dblk * 16 + dloc;

    const float A2 = -__expf(A_log[d * DS + n]) * 1.44269504088896f;
    float h = 0.f;

    __shared__ float s_B[32 * 16];
    __shared__ float s_delta[32];
    __shared__ float s_xc[32 * 16];

    const long rowbase = (long)bc * CL;
    for (int t0 = 0; t0 < CL; t0 += 32) {
        __syncthreads();
        for (int i = tid; i < 128; i += 256) {          // 32 rows x 16 cols, float4
            int r = i >> 2, cc = (i & 3) * 4;
            *(float4*)&s_B[r * 16 + cc] = *(const float4*)(proj + (rowbase + t0 + r) * PP + cc);
        }
        for (int i = tid - 128; i >= 0 && i < 128; i += 256) {
            int r = i >> 2, cc = (i & 3) * 4;
            *(float4*)&s_xc[r * 16 + cc] = *(const float4*)(xc + (rowbase + t0 + r) * DI + dblk * 16 + cc);
        }
        if (tid < 32) s_delta[tid] = delta[rowbase + t0 + tid];
        __syncthreads();
        #pragma unroll 8
        for (int r = 0; r < 32; r++) {
            float Bn = s_B[r * 16 + n];
            float dt = s_delta[r];
            float xv = s_xc[r * 16 + dloc];
            float a = __builtin_amdgcn_exp2f(dt * A2);
            h = fmaf(a, h, (dt * xv) * Bn);
        }
    }
    Hout[(long)bc * (DI * DS) + d * DS + n] = h;
}

// ---------- phase 2: sequential combine over chunks per (b,d,n) channel ----------
__global__ __launch_bounds__(256) void combine_k(const float* __restrict__ Hout,
                                                 const float* __restrict__ Dsum,
                                                 const float* __restrict__ A_log,
                                                 float* __restrict__ Hin) {
    int idx = blockIdx.x * 256 + threadIdx.x;   // 2*32768
    int b = idx >> 15;
    int rem = idx & 32767;                      // d*16+n
    const float A2 = -__expf(A_log[rem]) * 1.44269504088896f;
    float h = 0.f;
    #pragma unroll
    for (int c = 0; c < NC - 1; c++) {
        long o = (long)(b * NC + c) * (DI * DS) + rem;
        Hin[o] = h;
        h = fmaf(__builtin_amdgcn_exp2f(A2 * Dsum[b * NC + c]), h, Hout[o]);
    }
    Hin[(long)(b * NC + NC - 1) * (DI * DS) + rem] = h;
}

// ---------- pass 2: full scan with h0 = Hin, fused epilogue ----------
// R9 lesson: per-r predicated epilogue costs full-wave issue (VALUBusy 92%, 2x dur).
// Now: lane n==15 stashes reduced p into s_y (1 ds_write/r); after each 32-r tile,
// a vectorized epilogue (2 outputs/thread, 100% lanes) does silu+f2bf+packed store.
__global__ __launch_bounds__(256) void scan_chunk(const float* __restrict__ xc,
                                                  const float* __restrict__ proj,
                                                  const float* __restrict__ delta,
                                                  const float* __restrict__ A_log,
                                                  const float* __restrict__ Hin,
                                                  const float* __restrict__ xz,
                                                  const float* __restrict__ Dp,
                                                  short* __restrict__ ybf) {
    const int bx = blockIdx.x;          // ((b*NC + c) * 128) + dblk
    const int dblk = bx & 127;
    const int bc = bx >> 7;
    const int tid  = threadIdx.x;
    const int w    = tid >> 6, lane = tid & 63;
    const int dq = lane >> 4, n = lane & 15;
    const int dloc = w * 4 + dq;
    const int d = dblk * 16 + dloc;

    const float A2 = -__expf(A_log[d * DS + n]) * 1.44269504088896f;
    float h = Hin[(long)bc * (DI * DS) + d * DS + n];

    // epilogue role: thread -> row er = tid>>3, d-pair ej = (tid&7)*2
    const int er = tid >> 3;
    const int ej = (tid & 7) * 2;
    const float Dv0 = Dp[dblk * 16 + ej];
    const float Dv1 = Dp[dblk * 16 + ej + 1];

    __shared__ float s_BC[32 * 32];     // cols 0..31 of proj (B then C)
    __shared__ float s_delta[32];
    __shared__ float s_xc[32 * 16];
    __shared__ float s_z[32 * 16];
    __shared__ float s_y[32 * 16];

    const long rowbase = (long)bc * CL;
    for (int t0 = 0; t0 < CL; t0 += 32) {
        __syncthreads();
        {
            int r = tid >> 3, cc = (tid & 7) * 4;       // 32 rows x 32 cols, float4
            *(float4*)&s_BC[r * 32 + cc] = *(const float4*)(proj + (rowbase + t0 + r) * PP + cc);
        }
        for (int i = tid; i < 128; i += 256) {
            int r = i >> 2, cc = (i & 3) * 4;
            *(float4*)&s_xc[r * 16 + cc] = *(const float4*)(xc + (rowbase + t0 + r) * DI + dblk * 16 + cc);
            *(float4*)&s_z[r * 16 + cc]  = *(const float4*)(xz + (rowbase + t0 + r) * 4096 + DI + dblk * 16 + cc);
        }
        if (tid < 32) s_delta[tid] = delta[rowbase + t0 + tid];
        __syncthreads();
        #pragma unroll 8
        for (int r = 0; r < 32; r++) {
            float Bn    = s_BC[r * 32 + n];
            float Cn    = s_BC[r * 32 + 16 + n];
            float dt    = s_delta[r];
            float xv    = s_xc[r * 16 + dloc];
            float a = __builtin_amdgcn_exp2f(dt * A2);
            h = fmaf(a, h, (dt * xv) * Bn);
            float p = h * Cn;
            p += dpp_shr<0x111>(p);
            p += dpp_shr<0x112>(p);
            p += dpp_shr<0x114>(p);
            p += dpp_shr<0x118>(p);
            if (n == 15) s_y[r * 16 + dloc] = p;
        }
        __syncthreads();
        // vectorized epilogue: 512 outputs, 2 adjacent d per thread, all lanes active
        {
            float2 yv = *(float2*)&s_y[er * 16 + ej];
            float2 xv = *(float2*)&s_xc[er * 16 + ej];
            float2 zv = *(float2*)&s_z[er * 16 + ej];
            float v0 = (yv.x + xv.x * Dv0) * (zv.x / (1.f + __expf(-zv.x)));
            float v1 = (yv.y + xv.y * Dv1) * (zv.y / (1.f + __expf(-zv.y)));
            unsigned o = (unsigned)(unsigned short)f2bf(v0)
                       | ((unsigned)(unsigned short)f2bf(v1) << 16);
            *(unsigned*)&ybf[(rowbase + t0 + er) * 8192 + dblk * 16 + ej] = o;
        }
    }
}

// ---------- launch ----------
extern "C" void kernel_launch(void* const* d_in, const int* in_sizes, int n_in,
                              void* d_out, int out_size, void* d_ws, size_t ws_size,
                              hipStream_t stream) {
    const float* x      = (const float*)d_in[0];
    const float* W_in   = (const float*)d_in[1];
    const float* b_in   = (const float*)d_in[2];
    const float* conv_w = (const float*)d_in[3];
    const float* conv_b = (const float*)d_in[4];
    const float* W_xprj = (const float*)d_in[5];
    const float* A_log  = (const float*)d_in[6];
    const float* D_par  = (const float*)d_in[7];
    const float* W_out  = (const float*)d_in[8];
    const float* b_out  = (const float*)d_in[9];
    float* out = (float*)d_out;
    char* ws = (char*)d_ws;

    // workspace layout (bytes) — high-water ~122.5 MB
    const size_t OFF_XBF  = 0;              // 8 MB (dead after gemm1)
    const size_t OFF_WINT = 8388608;        // 8 MB (dead after gemm1)
    const size_t OFF_HOUT = 0;              // 2 MB, overlays dead xbf
    const size_t OFF_HIN  = 2097152;        // 2 MB
    const size_t OFF_WOT  = 16777216;       // 4 MB
    const size_t OFF_DELTA= 20971520;       // 16 KB
    const size_t OFF_DSUM = 21004288;       // 64 B
    const size_t OFF_XZ   = 21241856;       // 64 MB (x_ssm half becomes ybf)
    const size_t OFF_XC   = 88350720;       // 32 MB
    const size_t OFF_PROJ = 121905152;      // 4096*36*4 = 590 KB

    short* xbf  = (short*)(ws + OFF_XBF);
    short* WinT = (short*)(ws + OFF_WINT);
    short* WoT  = (short*)(ws + OFF_WOT);
    float* Hout = (float*)(ws + OFF_HOUT);
    float* Hin  = (float*)(ws + OFF_HIN);
    float* delta= (float*)(ws + OFF_DELTA);
    float* Dsum = (float*)(ws + OFF_DSUM);
    float* xz   = (float*)(ws + OFF_XZ);
    float* xc   = (float*)(ws + OFF_XC);
    float* proj = (float*)(ws + OFF_PROJ);
    short* ybf  = (short*)(ws + OFF_XZ);    // bf16, row stride 8192 (x_ssm half of xz)

    convert_x_k<<<4096, 256, 0, stream>>>(x, xbf);
    transpose_to_bf16<<<dim3(128, 32), 256, 0, stream>>>(W_in, WinT, 1024, 4096);
    transpose_to_bf16<<<dim3(32, 64), 256, 0, stream>>>(W_out, WoT, 2048, 1024);

    gemm_bt<<<dim3(32, 32), 256, 0, stream>>>(xbf, 1024, WinT, 1024, xz, b_in, NROW, 4096, 1024);
    conv_silu_k<<<8192, 256, 0, stream>>>(xz, conv_w, conv_b, xc);
    proj_gemm<<<1024, 256, 0, stream>>>(xc, W_xprj, proj);
    delta_k<<<B_SZ * NC, 256, 0, stream>>>(proj, delta, Dsum);
    scan_part1<<<B_SZ * (NC - 1) * 128, 256, 0, stream>>>(xc, proj, delta, A_log, Hout);
    combine_k<<<256, 256, 0, stream>>>(Hout, Dsum, A_log, Hin);
    scan_chunk<<<B_SZ * NC * 128, 256, 0, stream>>>(xc, proj, delta, A_log, Hin, xz, D_par, ybf);
    gemm_bt<<<dim3(8, 32), 256, 0, stream>>>(ybf, 8192, WoT, 2048, out, b_out, NROW, 1024, 2048);
}